// Round 1
// baseline (378.289 us; speedup 1.0000x reference)
//
#include <hip/hip_runtime.h>
#include <hip/hip_bf16.h>
#include <stdint.h>

#define M_DIM 8192
#define N_DIM 4096
#define K_DIM 4096
#define BM 128
#define BN 128
#define BK 32

typedef __attribute__((ext_vector_type(8))) short short8;
typedef __attribute__((ext_vector_type(4))) float f32x4;
typedef unsigned short ushort_t;

// ---------- fp32 -> bf16 (RNE) conversion ----------
__device__ __forceinline__ ushort_t f2bf(float f) {
    uint32_t u = __float_as_uint(f);
    uint32_t r = (u + 0x7FFFu + ((u >> 16) & 1u)) >> 16;
    return (ushort_t)r;
}

__global__ void cvt_f32_bf16(const float4* __restrict__ in, ushort* __restrict__ out4, int n4) {
    int i = blockIdx.x * blockDim.x + threadIdx.x;
    if (i < n4) {
        float4 v = in[i];
        ushort_t a = f2bf(v.x), b = f2bf(v.y), c = f2bf(v.z), d = f2bf(v.w);
        uint32_t lo = (uint32_t)a | ((uint32_t)b << 16);
        uint32_t hi = (uint32_t)c | ((uint32_t)d << 16);
        uint2* o = reinterpret_cast<uint2*>(out4);
        o[i] = make_uint2(lo, hi);
    }
}

// ---------- async global -> LDS, 16B per lane ----------
__device__ __forceinline__ void gload_lds16(const ushort_t* g, ushort_t* l) {
    __builtin_amdgcn_global_load_lds(
        (const __attribute__((address_space(1))) unsigned int*)g,
        (__attribute__((address_space(3))) unsigned int*)l,
        16, 0, 0);
}

// ---------- fused GEMM (x @ W^T) + GroupNorm + bias + clamp ----------
// grid: (M/BM)*(N/BN) blocks of 256 threads (4 waves, 2x2).
// BN == group_size == 128, so each block column is exactly one group.
__global__ __launch_bounds__(256, 2)
void gemm_gn_kernel(const ushort_t* __restrict__ xb,   // [M][K] bf16
                    const ushort_t* __restrict__ wb,   // [N][K] bf16
                    const float*   __restrict__ bias,  // [N]
                    float*         __restrict__ out)   // [M][N]
{
    __shared__ ushort_t As[BM * BK];   // 8 KB
    __shared__ ushort_t Bs[BN * BK];   // 8 KB
    __shared__ float redS [2][BM];     // cross-wave col-sum
    __shared__ float redS2[2][BM];     // cross-wave col-sumsq

    const int tid = threadIdx.x;
    const int w   = tid >> 6;          // wave 0..3
    const int l   = tid & 63;
    const int wr  = w >> 1;            // wave row (0..1)
    const int wc  = w & 1;             // wave col (0..1)
    const int l15 = l & 15;
    const int l4  = l >> 4;

    const int TN   = N_DIM / BN;       // 32 tiles in N
    const int bid  = blockIdx.x;
    const int brow = (bid / TN) * BM;
    const int bcol = (bid % TN) * BN;

    f32x4 acc[4][4];
#pragma unroll
    for (int i = 0; i < 4; ++i)
#pragma unroll
        for (int j = 0; j < 4; ++j) acc[i][j] = (f32x4){0.f, 0.f, 0.f, 0.f};

    // staging: thread t covers linear bf16 elems [t*8, t*8+8) of the row-major
    // [128][32] tile; issue i adds 64 rows (2048 elems).
    const int srow = tid >> 2;
    const int scol = (tid & 3) * 8;
    const ushort_t* ga0 = xb + (size_t)(brow + srow)      * K_DIM + scol;
    const ushort_t* ga1 = xb + (size_t)(brow + 64 + srow) * K_DIM + scol;
    const ushort_t* gb0 = wb + (size_t)(bcol + srow)      * K_DIM + scol;
    const ushort_t* gb1 = wb + (size_t)(bcol + 64 + srow) * K_DIM + scol;
    ushort_t* lA0 = As + w * 512;          // wave-uniform LDS bases
    ushort_t* lA1 = As + 2048 + w * 512;
    ushort_t* lB0 = Bs + w * 512;
    ushort_t* lB1 = Bs + 2048 + w * 512;

    // fragment LDS element offsets
    const int aoff = (wr * 64 + l15) * BK + l4 * 8;
    const int boff = (wc * 64 + l15) * BK + l4 * 8;

    for (int kt = 0; kt < K_DIM / BK; ++kt) {
        const int k0 = kt * BK;
        __syncthreads();                       // prev ds_reads done
        gload_lds16(ga0 + k0, lA0);
        gload_lds16(ga1 + k0, lA1);
        gload_lds16(gb0 + k0, lB0);
        gload_lds16(gb1 + k0, lB1);
        __syncthreads();                       // staging done (vmcnt drained)

        short8 af[4], bf[4];
#pragma unroll
        for (int mi = 0; mi < 4; ++mi)
            af[mi] = *reinterpret_cast<const short8*>(&As[aoff + mi * 16 * BK]);
#pragma unroll
        for (int ni = 0; ni < 4; ++ni)
            bf[ni] = *reinterpret_cast<const short8*>(&Bs[boff + ni * 16 * BK]);
#pragma unroll
        for (int mi = 0; mi < 4; ++mi)
#pragma unroll
            for (int ni = 0; ni < 4; ++ni)
                acc[mi][ni] = __builtin_amdgcn_mfma_f32_16x16x32_bf16(
                    af[mi], bf[ni], acc[mi][ni], 0, 0, 0);
    }

    // ---------- fused GroupNorm epilogue ----------
    // C/D layout: col = l&15, row = (l>>4)*4 + reg  (per 16x16 fragment)
    float s[4][4], s2[4][4];
#pragma unroll
    for (int mi = 0; mi < 4; ++mi)
#pragma unroll
        for (int r = 0; r < 4; ++r) {
            float a = 0.f, b = 0.f;
#pragma unroll
            for (int ni = 0; ni < 4; ++ni) {
                float v = acc[mi][ni][r];
                a += v;
                b += v * v;
            }
            s[mi][r] = a;
            s2[mi][r] = b;
        }
    // reduce across the 16 lanes of each quarter-wave (cols within the wave)
#pragma unroll
    for (int mi = 0; mi < 4; ++mi)
#pragma unroll
        for (int r = 0; r < 4; ++r) {
#pragma unroll
            for (int m = 1; m < 16; m <<= 1) {
                s[mi][r]  += __shfl_xor(s[mi][r],  m);
                s2[mi][r] += __shfl_xor(s2[mi][r], m);
            }
        }

    __syncthreads();
    if (l15 == 0) {
#pragma unroll
        for (int mi = 0; mi < 4; ++mi)
#pragma unroll
            for (int r = 0; r < 4; ++r) {
                int R = wr * 64 + mi * 16 + l4 * 4 + r;
                redS [wc][R] = s[mi][r];
                redS2[wc][R] = s2[mi][r];
            }
    }
    __syncthreads();

    float bv[4];
#pragma unroll
    for (int ni = 0; ni < 4; ++ni)
        bv[ni] = bias[bcol + wc * 64 + ni * 16 + l15];

    const float inv_gs = 1.0f / 128.0f;
#pragma unroll
    for (int mi = 0; mi < 4; ++mi)
#pragma unroll
        for (int r = 0; r < 4; ++r) {
            int R = wr * 64 + mi * 16 + l4 * 4 + r;
            float S  = redS [0][R] + redS [1][R];
            float S2 = redS2[0][R] + redS2[1][R];
            float mean = S * inv_gs;
            float var  = S2 * inv_gs - mean * mean;
            float inv  = rsqrtf(var + 1e-6f);
            size_t rowbase = (size_t)(brow + R) * N_DIM + bcol + wc * 64 + l15;
#pragma unroll
            for (int ni = 0; ni < 4; ++ni) {
                float v = (acc[mi][ni][r] - mean) * inv + bv[ni];
                v = fminf(fmaxf(v, -2.0f), 2.0f);
                out[rowbase + ni * 16] = v;
            }
        }
}

extern "C" void kernel_launch(void* const* d_in, const int* in_sizes, int n_in,
                              void* d_out, int out_size, void* d_ws, size_t ws_size,
                              hipStream_t stream) {
    const float* x = (const float*)d_in[0];
    const float* W = (const float*)d_in[1];
    const float* b = (const float*)d_in[2];
    float* out = (float*)d_out;

    ushort_t* xb = (ushort_t*)d_ws;                       // 64 MB
    ushort_t* wb = xb + (size_t)M_DIM * K_DIM;            // +32 MB

    int n4x = M_DIM * K_DIM / 4;
    cvt_f32_bf16<<<(n4x + 255) / 256, 256, 0, stream>>>(
        (const float4*)x, xb, n4x);
    int n4w = N_DIM * K_DIM / 4;
    cvt_f32_bf16<<<(n4w + 255) / 256, 256, 0, stream>>>(
        (const float4*)W, wb, n4w);

    int grid = (M_DIM / BM) * (N_DIM / BN);               // 2048 blocks
    gemm_gn_kernel<<<grid, 256, 0, stream>>>(xb, wb, b, out);
}

// Round 2
// 367.107 us; speedup vs baseline: 1.0305x; 1.0305x over previous
//
#include <hip/hip_runtime.h>
#include <hip/hip_bf16.h>
#include <stdint.h>

#define M_DIM 8192
#define N_DIM 4096
#define K_DIM 4096
#define BM 256
#define BN 256
#define BK 32
#define NT (K_DIM / BK)   // 128

typedef __attribute__((ext_vector_type(8))) short short8;
typedef __attribute__((ext_vector_type(4))) float f32x4;
typedef unsigned short ushort_t;

// ---------- fp32 -> bf16 (RNE) conversion ----------
__device__ __forceinline__ ushort_t f2bf(float f) {
    uint32_t u = __float_as_uint(f);
    uint32_t r = (u + 0x7FFFu + ((u >> 16) & 1u)) >> 16;
    return (ushort_t)r;
}

__global__ void cvt_f32_bf16(const float4* __restrict__ in, ushort* __restrict__ out4, int n4) {
    int i = blockIdx.x * blockDim.x + threadIdx.x;
    if (i < n4) {
        float4 v = in[i];
        ushort_t a = f2bf(v.x), b = f2bf(v.y), c = f2bf(v.z), d = f2bf(v.w);
        uint32_t lo = (uint32_t)a | ((uint32_t)b << 16);
        uint32_t hi = (uint32_t)c | ((uint32_t)d << 16);
        uint2* o = reinterpret_cast<uint2*>(out4);
        o[i] = make_uint2(lo, hi);
    }
}

// ---------- async global -> LDS, 16B per lane ----------
__device__ __forceinline__ void gload_lds16(const ushort_t* g, void* l) {
    __builtin_amdgcn_global_load_lds(
        (const __attribute__((address_space(1))) unsigned int*)g,
        (__attribute__((address_space(3))) unsigned int*)l,
        16, 0, 0);
}

// ---------- fused GEMM (x @ W^T) + GroupNorm + bias + clamp ----------
// 256x256 tile, BK=32, 512 threads (8 waves 2Mx4N), triple-buffered LDS,
// counted-vmcnt pipeline (loads stay in flight across barriers).
__global__ __launch_bounds__(512, 2)
void gemm_gn_kernel(const ushort_t* __restrict__ xb,   // [M][K] bf16
                    const ushort_t* __restrict__ wb,   // [N][K] bf16
                    const float*   __restrict__ bias,  // [N]
                    float*         __restrict__ out)   // [M][N]
{
    __shared__ char pool[3 * 32768];   // 96 KiB: 3 x (A 16K + B 16K)

    const int tid = threadIdx.x;
    const int w   = tid >> 6;          // wave 0..7
    const int l   = tid & 63;
    const int wr  = w >> 2;            // 0..1  (M half)
    const int wc  = w & 3;             // 0..3  (N quarter)
    const int l15 = l & 15;
    const int l4  = l >> 4;

    // bijective XCD swizzle (512 = 8*64)
    const int TN = N_DIM / BN;         // 16
    int bid = blockIdx.x;
    bid = (bid & 7) * ((M_DIM / BM) * TN / 8) + (bid >> 3);
    const int brow = (bid / TN) * BM;
    const int bcol = (bid % TN) * BN;

    // ---- staging addressing (source pre-swizzled: slot ^= row&3) ----
    const int srow  = tid >> 2;                       // 0..127 (64B rows)
    const int sslot = (tid & 3) ^ (srow & 3);
    const ushort_t* gA0 = xb + (size_t)(brow + srow)       * K_DIM + sslot * 8;
    const ushort_t* gA1 = xb + (size_t)(brow + 128 + srow) * K_DIM + sslot * 8;
    const ushort_t* gB0 = wb + (size_t)(bcol + srow)       * K_DIM + sslot * 8;
    const ushort_t* gB1 = wb + (size_t)(bcol + 128 + srow) * K_DIM + sslot * 8;

    f32x4 acc[8][4];
#pragma unroll
    for (int i = 0; i < 8; ++i)
#pragma unroll
        for (int j = 0; j < 4; ++j) acc[i][j] = (f32x4){0.f, 0.f, 0.f, 0.f};

    // stage tile t (4 global_load_lds per thread) into buffer buf
    auto STAGE = [&](char* buf, int t) {
        const int k0 = t * BK;
        char* ldsA = buf + w * 1024;            // wave-uniform base
        gload_lds16(gA0 + k0, ldsA);
        gload_lds16(gA1 + k0, ldsA + 8192);
        char* ldsB = buf + 16384 + w * 1024;
        gload_lds16(gB0 + k0, ldsB);
        gload_lds16(gB1 + k0, ldsB + 8192);
    };

    // swizzled read offset within a 64B row
    const int sw = ((l4 ^ (l15 & 3)) << 4);
    const int arow0 = wr * 128 + l15;
    const int brow0 = wc * 64 + l15;

    auto COMPUTE = [&](char* buf) {
        const char* A = buf;
        const char* B = buf + 16384;
        short8 af[8], bf[4];
#pragma unroll
        for (int mi = 0; mi < 8; ++mi)
            af[mi] = *(const short8*)(A + (arow0 + mi * 16) * 64 + sw);
#pragma unroll
        for (int ni = 0; ni < 4; ++ni)
            bf[ni] = *(const short8*)(B + (brow0 + ni * 16) * 64 + sw);
        __builtin_amdgcn_s_setprio(1);
#pragma unroll
        for (int mi = 0; mi < 8; ++mi)
#pragma unroll
            for (int ni = 0; ni < 4; ++ni)
                acc[mi][ni] = __builtin_amdgcn_mfma_f32_16x16x32_bf16(
                    af[mi], bf[ni], acc[mi][ni], 0, 0, 0);
        __builtin_amdgcn_s_setprio(0);
    };

    char* b0 = pool;
    char* b1 = pool + 32768;
    char* b2 = pool + 65536;
    STAGE(b0, 0);
    STAGE(b1, 1);
    STAGE(b2, 2);
    char* cur = b0; char* nxt = b1; char* fut = b2;

    for (int t = 0; t < NT; ++t) {
        // ensure tile t landed; keep up to 2 tiles (8 loads) in flight
        if (t < NT - 2)       { asm volatile("s_waitcnt vmcnt(8)" ::: "memory"); }
        else if (t == NT - 2) { asm volatile("s_waitcnt vmcnt(4)" ::: "memory"); }
        else                  { asm volatile("s_waitcnt vmcnt(0)" ::: "memory"); }
        asm volatile("s_barrier" ::: "memory");      // tile t visible to all waves

        COMPUTE(cur);

        asm volatile("s_waitcnt lgkmcnt(0)" ::: "memory");  // my reads of cur retired
        asm volatile("s_barrier" ::: "memory");             // all waves' reads retired
        if (t + 3 < NT) STAGE(cur, t + 3);                  // overwrite just-consumed buffer
        char* tmp = cur; cur = nxt; nxt = fut; fut = tmp;
    }

    // ---------- fused GroupNorm epilogue ----------
    // C/D: col = l15 (+ni*16 + wc*64), row = l4*4 + reg (+mi*16 + wr*128)
    float s[8][4], s2[8][4];
#pragma unroll
    for (int mi = 0; mi < 8; ++mi)
#pragma unroll
        for (int r = 0; r < 4; ++r) {
            float a = 0.f, b = 0.f;
#pragma unroll
            for (int ni = 0; ni < 4; ++ni) {
                float v = acc[mi][ni][r];
                a += v;
                b += v * v;
            }
#pragma unroll
            for (int m = 1; m < 16; m <<= 1) {
                a += __shfl_xor(a, m);
                b += __shfl_xor(b, m);
            }
            s[mi][r] = a;
            s2[mi][r] = b;
        }

    float* redS  = (float*)pool;          // [256][4]
    float* redS2 = (float*)(pool + 4096); // [256][4]
    if (l15 == 0) {
#pragma unroll
        for (int mi = 0; mi < 8; ++mi)
#pragma unroll
            for (int r = 0; r < 4; ++r) {
                int R = wr * 128 + mi * 16 + l4 * 4 + r;
                redS [R * 4 + wc] = s[mi][r];
                redS2[R * 4 + wc] = s2[mi][r];
            }
    }
    __syncthreads();

    float bv[4];
#pragma unroll
    for (int ni = 0; ni < 4; ++ni)
        bv[ni] = bias[bcol + wc * 64 + ni * 16 + l15];

    const int g2 = (wc >> 1) * 2;          // group base (pair of wc quarters)
    const float inv_gs = 1.0f / 128.0f;
#pragma unroll
    for (int mi = 0; mi < 8; ++mi)
#pragma unroll
        for (int r = 0; r < 4; ++r) {
            int R = wr * 128 + mi * 16 + l4 * 4 + r;
            float S  = redS [R * 4 + g2] + redS [R * 4 + g2 + 1];
            float S2 = redS2[R * 4 + g2] + redS2[R * 4 + g2 + 1];
            float mean = S * inv_gs;
            float var  = S2 * inv_gs - mean * mean;
            float inv  = rsqrtf(var + 1e-6f);
            size_t rowbase = (size_t)(brow + R) * N_DIM + bcol + wc * 64 + l15;
#pragma unroll
            for (int ni = 0; ni < 4; ++ni) {
                float v = (acc[mi][ni][r] - mean) * inv + bv[ni];
                v = fminf(fmaxf(v, -2.0f), 2.0f);
                out[rowbase + ni * 16] = v;
            }
        }
}

extern "C" void kernel_launch(void* const* d_in, const int* in_sizes, int n_in,
                              void* d_out, int out_size, void* d_ws, size_t ws_size,
                              hipStream_t stream) {
    const float* x = (const float*)d_in[0];
    const float* W = (const float*)d_in[1];
    const float* b = (const float*)d_in[2];
    float* out = (float*)d_out;

    ushort_t* xb = (ushort_t*)d_ws;                       // 64 MB
    ushort_t* wb = xb + (size_t)M_DIM * K_DIM;            // +32 MB

    int n4x = M_DIM * K_DIM / 4;
    cvt_f32_bf16<<<(n4x + 255) / 256, 256, 0, stream>>>(
        (const float4*)x, xb, n4x);
    int n4w = N_DIM * K_DIM / 4;
    cvt_f32_bf16<<<(n4w + 255) / 256, 256, 0, stream>>>(
        (const float4*)W, wb, n4w);

    int grid = (M_DIM / BM) * (N_DIM / BN);               // 512 blocks
    gemm_gn_kernel<<<grid, 512, 0, stream>>>(xb, wb, b, out);
}

// Round 3
// 325.976 us; speedup vs baseline: 1.1605x; 1.1262x over previous
//
#include <hip/hip_runtime.h>
#include <hip/hip_bf16.h>
#include <stdint.h>

#define M_DIM 8192
#define N_DIM 4096
#define K_DIM 4096
#define BM 256
#define BN 256
#define BK 64
#define NTILES (K_DIM / BK)   // 64

typedef __attribute__((ext_vector_type(8))) short short8;
typedef __attribute__((ext_vector_type(4))) float f32x4;
typedef unsigned short ushort_t;

#define SBAR()      asm volatile("s_barrier" ::: "memory")
#define WAIT_LGKM0() asm volatile("s_waitcnt lgkmcnt(0)" ::: "memory")

// ---------- fp32 -> bf16 (RNE) conversion ----------
__device__ __forceinline__ ushort_t f2bf(float f) {
    uint32_t u = __float_as_uint(f);
    uint32_t r = (u + 0x7FFFu + ((u >> 16) & 1u)) >> 16;
    return (ushort_t)r;
}

__global__ void cvt_f32_bf16(const float4* __restrict__ in, ushort* __restrict__ out4, int n4) {
    int i = blockIdx.x * blockDim.x + threadIdx.x;
    if (i < n4) {
        float4 v = in[i];
        ushort_t a = f2bf(v.x), b = f2bf(v.y), c = f2bf(v.z), d = f2bf(v.w);
        uint32_t lo = (uint32_t)a | ((uint32_t)b << 16);
        uint32_t hi = (uint32_t)c | ((uint32_t)d << 16);
        uint2* o = reinterpret_cast<uint2*>(out4);
        o[i] = make_uint2(lo, hi);
    }
}

// ---------- async global -> LDS, 16B per lane ----------
__device__ __forceinline__ void gload_lds16(const ushort_t* g, void* l) {
    __builtin_amdgcn_global_load_lds(
        (const __attribute__((address_space(1))) unsigned int*)g,
        (__attribute__((address_space(3))) unsigned int*)l,
        16, 0, 0);
}

// ---------- fused GEMM (x @ W^T) + GroupNorm + bias + clamp ----------
// 256x256 tile, BK=64, 512 threads (8 waves 2Mx4N), 2x64KB LDS dbuf,
// m201-style 4-phase/tile schedule with half-tile stage stagger + counted vmcnt.
__global__ __launch_bounds__(512, 2)
void gemm_gn_kernel(const ushort_t* __restrict__ xb,   // [M][K] bf16
                    const ushort_t* __restrict__ wb,   // [N][K] bf16
                    const float*   __restrict__ bias,  // [N]
                    float*         __restrict__ out)   // [M][N]
{
    __shared__ char pool[131072];   // 2 buf x (A 32K [256][128B] + B 32K)

    const int tid = threadIdx.x;
    const int w   = tid >> 6;          // wave 0..7
    const int l   = tid & 63;
    const int wr  = w >> 2;            // 0..1  (M half)
    const int wc  = w & 3;             // 0..3  (N quarter)
    const int l15 = l & 15;
    const int l4  = l >> 4;

    // bijective XCD swizzle (512 = 8*64)
    const int TN = N_DIM / BN;         // 16
    int bid = blockIdx.x;
    bid = (bid & 7) * ((M_DIM / BM) * TN / 8) + (bid >> 3);
    const int brow = (bid / TN) * BM;
    const int bcol = (bid % TN) * BN;

    // ---- staging: half-tile = 128 rows x 64k = 16KB = 512thr x 2loads x 16B
    // LDS dest linear; global SOURCE pre-swizzled: slot ^= row&7  (rule #21)
    const int srow8 = tid >> 3;                      // 0..63
    const int sslot = (tid & 7) ^ (srow8 & 7);
    const ushort_t* gA = xb + (size_t)(brow + srow8) * K_DIM + sslot * 8;
    const ushort_t* gB = wb + (size_t)(bcol + srow8) * K_DIM + sslot * 8;
    const size_t ROW64 = (size_t)64 * K_DIM;
    const int wave1024 = w * 1024;

    auto STAGE = [&](int buf, int isB, int h, int kt) {
        const ushort_t* src = (isB ? gB : gA) + (size_t)h * 128 * K_DIM + (size_t)kt * 64;
        char* dst = pool + buf * 65536 + isB * 32768 + h * 16384 + wave1024;
        gload_lds16(src, dst);
        gload_lds16(src + ROW64, dst + 8192);
    };

    f32x4 acc[8][4];
#pragma unroll
    for (int i = 0; i < 8; ++i)
#pragma unroll
        for (int j = 0; j < 4; ++j) acc[i][j] = (f32x4){0.f, 0.f, 0.f, 0.f};

    // fragment read addressing (XOR-swizzled, row&7 == l15&7)
    const int swz = (l15 & 7) << 4;
    const int x0  = (l4 * 16) ^ swz;          // k-slice 0
    const int x1  = (64 + l4 * 16) ^ swz;     // k-slice 1
    const int abase = (wr * 128 + l15) * 128;
    const int bbase = (wc * 64  + l15) * 128;

    // ---- prologue: t0 {Blo,Bhi,Alo,Ahi}, t1 {Blo,Bhi}; t1-B may stay in flight
    STAGE(0, 1, 0, 0); STAGE(0, 1, 1, 0);
    STAGE(0, 0, 0, 0); STAGE(0, 0, 1, 0);
    STAGE(1, 1, 0, 1); STAGE(1, 1, 1, 1);
    asm volatile("s_waitcnt vmcnt(4)" ::: "memory");
    SBAR();

    short8 af[8], bf[8];

    for (int T = 0; T < NTILES; ++T) {
        const char* Ab = pool + (T & 1) * 65536;
        const char* Bb = Ab + 32768;

        // ---- phase 1: read A[m0-3]x2k (8) + B[n0-1]x2k (4); stage (T+1) A-lo
#pragma unroll
        for (int m = 0; m < 4; ++m) {
            af[m * 2]     = *(const short8*)(Ab + abase + m * 2048 + x0);
            af[m * 2 + 1] = *(const short8*)(Ab + abase + m * 2048 + x1);
        }
#pragma unroll
        for (int n = 0; n < 2; ++n) {
            bf[n * 2]     = *(const short8*)(Bb + bbase + n * 2048 + x0);
            bf[n * 2 + 1] = *(const short8*)(Bb + bbase + n * 2048 + x1);
        }
        if (T + 1 < NTILES) STAGE((T + 1) & 1, 0, 0, T + 1);
        asm volatile("s_waitcnt lgkmcnt(8)" ::: "memory");
        SBAR(); WAIT_LGKM0();
        __builtin_amdgcn_s_setprio(1);
#pragma unroll
        for (int m = 0; m < 4; ++m)
#pragma unroll
            for (int n = 0; n < 2; ++n) {
                acc[m][n] = __builtin_amdgcn_mfma_f32_16x16x32_bf16(af[m*2],   bf[n*2],   acc[m][n], 0, 0, 0);
                acc[m][n] = __builtin_amdgcn_mfma_f32_16x16x32_bf16(af[m*2+1], bf[n*2+1], acc[m][n], 0, 0, 0);
            }
        __builtin_amdgcn_s_setprio(0);
        SBAR();

        // ---- phase 2: read B[n2-3]x2k (4); stage (T+1) A-hi
#pragma unroll
        for (int n = 2; n < 4; ++n) {
            bf[n * 2]     = *(const short8*)(Bb + bbase + n * 2048 + x0);
            bf[n * 2 + 1] = *(const short8*)(Bb + bbase + n * 2048 + x1);
        }
        if (T + 1 < NTILES) STAGE((T + 1) & 1, 0, 1, T + 1);
        SBAR(); WAIT_LGKM0();
        __builtin_amdgcn_s_setprio(1);
#pragma unroll
        for (int m = 0; m < 4; ++m)
#pragma unroll
            for (int n = 2; n < 4; ++n) {
                acc[m][n] = __builtin_amdgcn_mfma_f32_16x16x32_bf16(af[m*2],   bf[n*2],   acc[m][n], 0, 0, 0);
                acc[m][n] = __builtin_amdgcn_mfma_f32_16x16x32_bf16(af[m*2+1], bf[n*2+1], acc[m][n], 0, 0, 0);
            }
        __builtin_amdgcn_s_setprio(0);
        SBAR();

        // ---- phase 3: read A[m4-7]x2k (8, overwrite); stage (T+2) B-lo (curr buf)
#pragma unroll
        for (int m = 0; m < 4; ++m) {
            af[m * 2]     = *(const short8*)(Ab + abase + (m + 4) * 2048 + x0);
            af[m * 2 + 1] = *(const short8*)(Ab + abase + (m + 4) * 2048 + x1);
        }
        if (T + 2 < NTILES) STAGE(T & 1, 1, 0, T + 2);
        SBAR(); WAIT_LGKM0();
        __builtin_amdgcn_s_setprio(1);
#pragma unroll
        for (int m = 0; m < 4; ++m)
#pragma unroll
            for (int n = 0; n < 2; ++n) {
                acc[4+m][n] = __builtin_amdgcn_mfma_f32_16x16x32_bf16(af[m*2],   bf[n*2],   acc[4+m][n], 0, 0, 0);
                acc[4+m][n] = __builtin_amdgcn_mfma_f32_16x16x32_bf16(af[m*2+1], bf[n*2+1], acc[4+m][n], 0, 0, 0);
            }
        __builtin_amdgcn_s_setprio(0);
        SBAR();

        // ---- phase 4: stage (T+2) B-hi; counted vmcnt (once per tile)
        if (T + 2 < NTILES) STAGE(T & 1, 1, 1, T + 2);
        if (T < NTILES - 2) { asm volatile("s_waitcnt vmcnt(4)" ::: "memory"); }
        else                { asm volatile("s_waitcnt vmcnt(0)" ::: "memory"); }
        SBAR();
        __builtin_amdgcn_s_setprio(1);
#pragma unroll
        for (int m = 0; m < 4; ++m)
#pragma unroll
            for (int n = 2; n < 4; ++n) {
                acc[4+m][n] = __builtin_amdgcn_mfma_f32_16x16x32_bf16(af[m*2],   bf[n*2],   acc[4+m][n], 0, 0, 0);
                acc[4+m][n] = __builtin_amdgcn_mfma_f32_16x16x32_bf16(af[m*2+1], bf[n*2+1], acc[4+m][n], 0, 0, 0);
            }
        __builtin_amdgcn_s_setprio(0);
        SBAR();
    }

    __syncthreads();

    // ---------- fused GroupNorm epilogue (verified round 1/2) ----------
    // C/D: col = l15 (+n*16 + wc*64), row = l4*4 + reg (+m*16 + wr*128)
    float s[8][4], s2[8][4];
#pragma unroll
    for (int mi = 0; mi < 8; ++mi)
#pragma unroll
        for (int r = 0; r < 4; ++r) {
            float a = 0.f, b = 0.f;
#pragma unroll
            for (int ni = 0; ni < 4; ++ni) {
                float v = acc[mi][ni][r];
                a += v;
                b += v * v;
            }
#pragma unroll
            for (int m = 1; m < 16; m <<= 1) {
                a += __shfl_xor(a, m);
                b += __shfl_xor(b, m);
            }
            s[mi][r] = a;
            s2[mi][r] = b;
        }

    float* redS  = (float*)pool;          // [256][4]
    float* redS2 = (float*)(pool + 4096); // [256][4]
    if (l15 == 0) {
#pragma unroll
        for (int mi = 0; mi < 8; ++mi)
#pragma unroll
            for (int r = 0; r < 4; ++r) {
                int R = wr * 128 + mi * 16 + l4 * 4 + r;
                redS [R * 4 + wc] = s[mi][r];
                redS2[R * 4 + wc] = s2[mi][r];
            }
    }
    __syncthreads();

    float bv[4];
#pragma unroll
    for (int ni = 0; ni < 4; ++ni)
        bv[ni] = bias[bcol + wc * 64 + ni * 16 + l15];

    const int g2 = (wc >> 1) * 2;          // group = pair of wc quarters (128 ch)
    const float inv_gs = 1.0f / 128.0f;
#pragma unroll
    for (int mi = 0; mi < 8; ++mi)
#pragma unroll
        for (int r = 0; r < 4; ++r) {
            int R = wr * 128 + mi * 16 + l4 * 4 + r;
            float S  = redS [R * 4 + g2] + redS [R * 4 + g2 + 1];
            float S2 = redS2[R * 4 + g2] + redS2[R * 4 + g2 + 1];
            float mean = S * inv_gs;
            float var  = S2 * inv_gs - mean * mean;
            float inv  = rsqrtf(var + 1e-6f);
            size_t rowbase = (size_t)(brow + R) * N_DIM + bcol + wc * 64 + l15;
#pragma unroll
            for (int ni = 0; ni < 4; ++ni) {
                float v = (acc[mi][ni][r] - mean) * inv + bv[ni];
                v = fminf(fmaxf(v, -2.0f), 2.0f);
                out[rowbase + ni * 16] = v;
            }
        }
}

extern "C" void kernel_launch(void* const* d_in, const int* in_sizes, int n_in,
                              void* d_out, int out_size, void* d_ws, size_t ws_size,
                              hipStream_t stream) {
    const float* x = (const float*)d_in[0];
    const float* W = (const float*)d_in[1];
    const float* b = (const float*)d_in[2];
    float* out = (float*)d_out;

    ushort_t* xb = (ushort_t*)d_ws;                       // 64 MB
    ushort_t* wb = xb + (size_t)M_DIM * K_DIM;            // +32 MB

    int n4x = M_DIM * K_DIM / 4;
    cvt_f32_bf16<<<(n4x + 255) / 256, 256, 0, stream>>>(
        (const float4*)x, xb, n4x);
    int n4w = N_DIM * K_DIM / 4;
    cvt_f32_bf16<<<(n4w + 255) / 256, 256, 0, stream>>>(
        (const float4*)W, wb, n4w);

    int grid = (M_DIM / BM) * (N_DIM / BN);               // 512 blocks
    gemm_gn_kernel<<<grid, 512, 0, stream>>>(xb, wb, b, out);
}

// Round 4
// 311.551 us; speedup vs baseline: 1.2142x; 1.0463x over previous
//
#include <hip/hip_runtime.h>
#include <hip/hip_bf16.h>
#include <stdint.h>

#define M_DIM 8192
#define N_DIM 4096
#define K_DIM 4096
#define BM 256
#define BN 256
#define BK 64
#define NT 64

typedef __attribute__((ext_vector_type(8))) short short8;
typedef __attribute__((ext_vector_type(4))) float f32x4;
typedef unsigned short ushort_t;

#define SBAR()  asm volatile("s_barrier" ::: "memory")
#define LGKM(n) asm volatile("s_waitcnt lgkmcnt(" #n ")" ::: "memory")
#define VM(n)   asm volatile("s_waitcnt vmcnt(" #n ")" ::: "memory")
#define SCHEDB() __builtin_amdgcn_sched_barrier(0)

// ---------- fp32 -> bf16 (RNE) conversion ----------
__device__ __forceinline__ ushort_t f2bf(float f) {
    uint32_t u = __float_as_uint(f);
    uint32_t r = (u + 0x7FFFu + ((u >> 16) & 1u)) >> 16;
    return (ushort_t)r;
}

__global__ void cvt_f32_bf16(const float4* __restrict__ in, ushort* __restrict__ out4, int n4) {
    int i = blockIdx.x * blockDim.x + threadIdx.x;
    if (i < n4) {
        float4 v = in[i];
        ushort_t a = f2bf(v.x), b = f2bf(v.y), c = f2bf(v.z), d = f2bf(v.w);
        uint32_t lo = (uint32_t)a | ((uint32_t)b << 16);
        uint32_t hi = (uint32_t)c | ((uint32_t)d << 16);
        uint2* o = reinterpret_cast<uint2*>(out4);
        o[i] = make_uint2(lo, hi);
    }
}

__device__ __forceinline__ void gload_lds16(const ushort_t* g, void* l) {
    __builtin_amdgcn_global_load_lds(
        (const __attribute__((address_space(1))) unsigned int*)g,
        (__attribute__((address_space(3))) unsigned int*)l,
        16, 0, 0);
}

// ---------- fused GEMM (x @ W^T) + GroupNorm + bias + clamp ----------
// 256x256 tile, BK=64, 256 threads = 4 waves (1/SIMD), per-wave 128x128 out.
// acc 256 AGPR + 128 VGPR fragment banks; one-phase-lookahead ds_reads with
// counted lgkm; 4 barriers/tile; counted vmcnt(8); gray-code quadrant phases.
__global__ __launch_bounds__(256, 1)
void gemm_gn_kernel(const ushort_t* __restrict__ xb,   // [M][K] bf16
                    const ushort_t* __restrict__ wb,   // [N][K] bf16
                    const float*   __restrict__ bias,  // [N]
                    float*         __restrict__ out)   // [M][N]
{
    __shared__ char pool[131072];   // 2 buf x (A 32K [256 rows x 128B] + B 32K)

    const int tid = threadIdx.x;
    const int w   = tid >> 6;          // wave 0..3
    const int l   = tid & 63;
    const int wr  = w >> 1;            // 0..1 (M half)
    const int wc  = w & 1;             // 0..1 (N half == one GN group)
    const int l15 = l & 15;
    const int l4  = l >> 4;

    // bijective XCD swizzle (512 blocks = 8*64)
    const int TN = N_DIM / BN;         // 16
    int bid = blockIdx.x;
    bid = (bid & 7) * 64 + (bid >> 3);
    const int brow = (bid / TN) * BM;
    const int bcol = (bid % TN) * BN;

    // ---- staging: half = 128 rows x 64k = 16KB = 256thr x 4 gloads x 16B
    // LDS dest linear; global SOURCE pre-swizzled: slot ^= row&7 (rule #21)
    const int srow  = tid >> 3;                      // 0..31
    const int sslot = (tid & 7) ^ (srow & 7);
    const ushort_t* gA = xb + (size_t)(brow + srow) * K_DIM + sslot * 8;
    const ushort_t* gB = wb + (size_t)(bcol + srow) * K_DIM + sslot * 8;
    const int wbase = w * 1024;        // wave rows 8w..8w+7 per 32-row stripe

    auto STAGE_A = [&](int buf, int half, int kt) {
        const ushort_t* s = gA + (size_t)half * 128 * K_DIM + (size_t)kt * 64;
        char* d = pool + buf * 65536 + half * 16384 + wbase;
        gload_lds16(s,                      d);
        gload_lds16(s + (size_t)32 * K_DIM, d + 4096);
        gload_lds16(s + (size_t)64 * K_DIM, d + 8192);
        gload_lds16(s + (size_t)96 * K_DIM, d + 12288);
    };
    auto STAGE_B = [&](int buf, int half, int kt) {
        const ushort_t* s = gB + (size_t)half * 128 * K_DIM + (size_t)kt * 64;
        char* d = pool + buf * 65536 + 32768 + half * 16384 + wbase;
        gload_lds16(s,                      d);
        gload_lds16(s + (size_t)32 * K_DIM, d + 4096);
        gload_lds16(s + (size_t)64 * K_DIM, d + 8192);
        gload_lds16(s + (size_t)96 * K_DIM, d + 12288);
    };

    // fragment LDS addressing (XOR-swizzled: row&7 == l15&7)
    const int swz = (l15 & 7) << 4;
    const int x0  = (l4 * 16) ^ swz;          // k-slice 0
    const int x1  = (64 + l4 * 16) ^ swz;     // k-slice 1
    const int abase = (wr * 128 + l15) * 128;
    const int bbase = (wc * 128 + l15) * 128;

    short8 afL[8], afH[8], bfL[8], bfH[8];

    auto RD_A = [&](short8* dst, const char* Ab, int mi0) {
#pragma unroll
        for (int m = 0; m < 4; ++m) {
            dst[m * 2]     = *(const short8*)(Ab + abase + (mi0 + m) * 2048 + x0);
            dst[m * 2 + 1] = *(const short8*)(Ab + abase + (mi0 + m) * 2048 + x1);
        }
    };
    auto RD_B = [&](short8* dst, const char* Bb, int ni0) {
#pragma unroll
        for (int n = 0; n < 4; ++n) {
            dst[n * 2]     = *(const short8*)(Bb + bbase + (ni0 + n) * 2048 + x0);
            dst[n * 2 + 1] = *(const short8*)(Bb + bbase + (ni0 + n) * 2048 + x1);
        }
    };

    f32x4 acc[8][8];
#pragma unroll
    for (int i = 0; i < 8; ++i)
#pragma unroll
        for (int j = 0; j < 8; ++j) acc[i][j] = (f32x4){0.f, 0.f, 0.f, 0.f};

    auto MM = [&](short8* A, short8* B, int m0, int n0) {
#pragma unroll
        for (int k = 0; k < 2; ++k)
#pragma unroll
            for (int m = 0; m < 4; ++m)
#pragma unroll
                for (int n = 0; n < 4; ++n)
                    acc[m0 + m][n0 + n] = __builtin_amdgcn_mfma_f32_16x16x32_bf16(
                        A[m * 2 + k], B[n * 2 + k], acc[m0 + m][n0 + n], 0, 0, 0);
    };

    // ---- prologue: stage A(0),B(0),B(1); drain A0/B0; first fragment reads
    STAGE_A(0, 0, 0); STAGE_A(0, 1, 0);
    STAGE_B(0, 0, 0); STAGE_B(0, 1, 0);
    STAGE_B(1, 0, 1); STAGE_B(1, 1, 1);
    VM(8);                         // drains A0,B0; B(1) x8 stays in flight
    SBAR();
    RD_B(bfL, pool + 32768, 0);    // FIFO order: bfL before afL (matches steady)
    RD_A(afL, pool, 0);

    for (int T = 0; T < NT; ++T) {
        const int cb = T & 1;
        const char* Ab = pool + cb * 65536;
        const char* Bb = Ab + 32768;
        const char* Abn = pool + (cb ^ 1) * 65536;
        const char* Bbn = Abn + 32768;

        // ---- P1: MFMA (m-lo x n-lo); lookahead afH; stage A-lo(T+1)
        SBAR();                                   // #1 (tile boundary)
        RD_A(afH, Ab, 4);
        if (T + 1 < NT) STAGE_A(cb ^ 1, 0, T + 1);
        LGKM(8);                                  // drains bfL(T), afL(T); afH in flight
        SCHEDB();
        __builtin_amdgcn_s_setprio(1);
        MM(afL, bfL, 0, 0);
        __builtin_amdgcn_s_setprio(0);

        // ---- P2: MFMA (m-hi x n-lo); lookahead bfH; stage A-hi(T+1)
        SBAR();                                   // #2
        RD_B(bfH, Bb, 4);
        if (T + 1 < NT) STAGE_A(cb ^ 1, 1, T + 1);
        LGKM(8);                                  // drains afH; bfH in flight
        SCHEDB();
        __builtin_amdgcn_s_setprio(1);
        MM(afH, bfL, 4, 0);
        __builtin_amdgcn_s_setprio(0);

        // ---- P3: MFMA (m-hi x n-hi); stage B-lo(T+2); lookahead bfL'(T+1)
        if (T + 2 < NT) STAGE_B(cb, 0, T + 2);    // safe: bfL drains certified by #2
        LGKM(0);                                  // drain bfH before #3 (cheap)
        if (T < NT - 2) { VM(8); } else { VM(0); }  // drains B(T+1), A-lo(T+1)
        SBAR();                                   // #3
        SCHEDB();
        if (T + 1 < NT) RD_B(bfL, Bbn, 0);        // B-lo(T+1): staged T-1, drained above
        __builtin_amdgcn_s_setprio(1);
        MM(afH, bfH, 4, 4);
        __builtin_amdgcn_s_setprio(0);

        // ---- P4: MFMA (m-lo x n-hi); stage B-hi(T+2); lookahead afL'(T+1)
        if (T + 2 < NT) STAGE_B(cb, 1, T + 2);    // safe: bfH drains certified by #3
        if (T < NT - 2) { VM(8); } else { VM(0); }  // drains A-hi(T+1)
        SBAR();                                   // #4
        __builtin_amdgcn_s_setprio(1);
        MM(afL, bfH, 0, 4);
        __builtin_amdgcn_s_setprio(0);
        if (T + 1 < NT) RD_A(afL, Abn, 0);        // A-lo(T+1): certified by #4
    }

    // ---------- fused GroupNorm epilogue (pure in-wave: 128 cols = 1 group) ----------
    // C/D: col = l15 (+n*16 + wc*128), row = l4*4 + reg (+m*16 + wr*128)
    float bv[8];
#pragma unroll
    for (int ni = 0; ni < 8; ++ni)
        bv[ni] = bias[bcol + wc * 128 + ni * 16 + l15];

    const float inv_gs = 1.0f / 128.0f;
#pragma unroll
    for (int mi = 0; mi < 8; ++mi) {
#pragma unroll
        for (int r = 0; r < 4; ++r) {
            float a = 0.f, b = 0.f;
#pragma unroll
            for (int ni = 0; ni < 8; ++ni) {
                float v = acc[mi][ni][r];
                a += v;
                b += v * v;
            }
#pragma unroll
            for (int m = 1; m < 16; m <<= 1) {
                a += __shfl_xor(a, m);
                b += __shfl_xor(b, m);
            }
            float mean = a * inv_gs;
            float var  = b * inv_gs - mean * mean;
            float inv  = rsqrtf(var + 1e-6f);
            int R = wr * 128 + mi * 16 + l4 * 4 + r;
            size_t rowbase = (size_t)(brow + R) * N_DIM + bcol + wc * 128 + l15;
#pragma unroll
            for (int ni = 0; ni < 8; ++ni) {
                float v = (acc[mi][ni][r] - mean) * inv + bv[ni];
                v = fminf(fmaxf(v, -2.0f), 2.0f);
                out[rowbase + ni * 16] = v;
            }
        }
    }
}

extern "C" void kernel_launch(void* const* d_in, const int* in_sizes, int n_in,
                              void* d_out, int out_size, void* d_ws, size_t ws_size,
                              hipStream_t stream) {
    const float* x = (const float*)d_in[0];
    const float* W = (const float*)d_in[1];
    const float* b = (const float*)d_in[2];
    float* out = (float*)d_out;

    ushort_t* xb = (ushort_t*)d_ws;                       // 64 MB
    ushort_t* wb = xb + (size_t)M_DIM * K_DIM;            // +32 MB

    int n4x = M_DIM * K_DIM / 4;
    cvt_f32_bf16<<<(n4x + 255) / 256, 256, 0, stream>>>(
        (const float4*)x, xb, n4x);
    int n4w = N_DIM * K_DIM / 4;
    cvt_f32_bf16<<<(n4w + 255) / 256, 256, 0, stream>>>(
        (const float4*)W, wb, n4w);

    int grid = (M_DIM / BM) * (N_DIM / BN);               // 512 blocks
    gemm_gn_kernel<<<grid, 256, 0, stream>>>(xb, wb, b, out);
}